// Round 7
// baseline (1855.623 us; speedup 1.0000x reference)
//
#include <hip/hip_runtime.h>
#include <hip/hip_bf16.h>

typedef __attribute__((ext_vector_type(8))) short  short8;   // 8 x bf16 (MFMA frag)
typedef __attribute__((ext_vector_type(4))) float  f32x4;
typedef __attribute__((ext_vector_type(2))) unsigned int uint2v;
typedef unsigned long long u64;

#define NSTEPS 100
#define HSTEP  0.2f

// ---- RK45 (Dormand-Prince) coefficients ----
#define A21 (0.2f)
#define A31 (3.0f/40.0f)
#define A32 (9.0f/40.0f)
#define A41 (44.0f/45.0f)
#define A42 (-56.0f/15.0f)
#define A43 (32.0f/9.0f)
#define A51 (19372.0f/6561.0f)
#define A52 (-25360.0f/2187.0f)
#define A53 (64448.0f/6561.0f)
#define A54 (-212.0f/729.0f)
#define A61 (9017.0f/3168.0f)
#define A62 (-355.0f/33.0f)
#define A63 (46732.0f/5247.0f)
#define A64 (49.0f/176.0f)
#define A65 (-5103.0f/18656.0f)
#define B1  (35.0f/384.0f)
#define B3  (500.0f/1113.0f)
#define B4  (125.0f/192.0f)
#define B5  (-2187.0f/6784.0f)
#define B6  (11.0f/84.0f)

// d_ws layout (bytes):
//   [0,      512K)   Aw    : bf16 A in MFMA-frag order
//   [512K,   +8K )   sctr  : slow-path counters, 64 x 128B      (memset 0)
//   [520K,   +4K )   xtab  : XCD-placement votes, 64 x 64B      (memset 0)
//   [528K,   +32K)   fflag : fast-path flags, 64 x 4 x 128B     (memset 0)
//   [1M,     3M  )   Ybuf  : 2 parity x 64 g x 4 q x 4KB slices
#define WS_SCTR  (512u * 1024u)
#define WS_XTAB  (512u * 1024u + 8192u)
#define WS_FFLAG (512u * 1024u + 16384u)
#define WS_YB    (1024u * 1024u)

__device__ __forceinline__ unsigned short f2bf(float f) {
    union { float f; unsigned u; } v; v.f = f;
    unsigned r = v.u + 0x7FFFu + ((v.u >> 16) & 1u);   // RNE
    return (unsigned short)(r >> 16);
}

// Pack A (f32 row-major [row][k]) into bf16 MFMA A-fragment stream order:
// slot fk = T*16+kk, lane: holds A[T*16 + (lane&15)][kk*32 + (lane>>4)*8 + 0..7]
__global__ void pack_A_kernel(const float* __restrict__ A, short* __restrict__ Aw) {
    int t    = blockIdx.x * blockDim.x + threadIdx.x;   // 0..32767
    int lane = t & 63;
    int fk   = t >> 6;
    int kk   = fk & 15;
    int T    = fk >> 4;
    int row  = T * 16 + (lane & 15);
    int kb   = kk * 32 + (lane >> 4) * 8;
    const float* src = A + row * 512 + kb;
    short8 v;
#pragma unroll
    for (int e = 0; e < 8; ++e) v[e] = (short)f2bf(src[e]);
    *(short8*)(Aw + (size_t)t * 8) = v;
}

__global__ __launch_bounds__(512, 1) void mbpert_kernel(
    const float* __restrict__ x, const float* __restrict__ p,
    const float* __restrict__ r, const float* __restrict__ eps,
    const short* __restrict__ Aw, unsigned* __restrict__ sctr,
    unsigned* __restrict__ xtab, unsigned* __restrict__ fflag,
    u64* __restrict__ Ybuf, float* __restrict__ out)
{
    __shared__ __align__(16) char Ylds[16 * 1024];  // 512 rows x 16 cols bf16, swizzled
    __shared__ int s_fast;

    const int bid  = blockIdx.x;
    // peers-co-XCD remap (round-robin heuristic: bid%8 = XCD). bid = xcd + 8q + 32t
    const int q    = (bid >> 3) & 3;                 // row quarter
    const int g    = ((bid & 7) << 3) | (bid >> 5);  // column group, 0..63
    const int tid  = threadIdx.x;
    const int wave = tid >> 6;
    const int lane = tid & 63;
    const int cl   = lane & 15;
    const int gq   = lane >> 4;
    const int col  = g * 16 + cl;
    const int swz  = (cl & 7) << 4;
    const int rloc = wave * 16 + gq * 4;   // local row base (0..127)
    const int rg   = q * 128 + rloc;       // global row base

    unsigned* cptr  = sctr  + g * 32;      // slow-path counter (128B apart)
    unsigned* fbase = fflag + g * 128;     // fast-path flags: + q*32 (128B apart)

    // ---- A-fragments into VGPRs, once (A is constant across all 600 stages) ----
    short8 afrag[16];
    {
        const int T = q * 8 + wave;        // global 16-row tile owned by this wave
#pragma unroll
        for (int kk = 0; kk < 16; ++kk)
            afrag[kk] = *(const short8*)(Aw + ((size_t)(T * 16 + kk) * 64 + lane) * 8);
    }

    // ---- per-thread state ----
    f32x4 X0, W;
    X0 = *(const f32x4*)(x + col * 512 + rg);
#pragma unroll
    for (int j = 0; j < 4; ++j) {
        const int row = rg + j;
        W[j] = r[row] + eps[row] * p[row * 1024 + col];
    }

    // ---- placement probe: are all 4 peers on one XCD? ----
    unsigned my_xcc = 0;
    asm volatile("s_getreg_b32 %0, hwreg(HW_REG_XCC_ID)" : "=s"(my_xcc));
    if (tid == 0) {
        unsigned* xt = xtab + g * 16;
        __hip_atomic_fetch_or(xt, ((my_xcc & 0x7fu) + 1u) << (8 * q),
                              __ATOMIC_RELAXED, __HIP_MEMORY_SCOPE_AGENT);
        unsigned v;
        for (;;) {
            v = __hip_atomic_load(xt, __ATOMIC_RELAXED, __HIP_MEMORY_SCOPE_AGENT);
            if ((v & 0xffu) && (v & 0xff00u) && (v & 0xff0000u) && (v & 0xff000000u)) break;
            __builtin_amdgcn_s_sleep(1);
        }
        unsigned b0 = v & 0xffu;
        s_fast = (((v >> 8) & 0xffu) == b0) && (((v >> 16) & 0xffu) == b0) &&
                 (((v >> 24) & 0xffu) == b0);
    }
    __syncthreads();
    const bool fastp = (s_fast != 0);

    int ex = 0;   // exchange index 0..599

    // shared MFMA tail: full Y in Ylds -> Z = A_rows @ Y (A from VGPRs)
    auto do_mm = [&]() -> f32x4 {
        f32x4 acc = (f32x4){0.f, 0.f, 0.f, 0.f};
#pragma unroll
        for (int kk = 0; kk < 16; ++kk) {
            short8 b = *(const short8*)(Ylds + cl * 1024 + ((kk * 64 + gq * 16) ^ swz));
            acc = __builtin_amdgcn_mfma_f32_16x16x32_bf16(afrag[kk], b, acc, 0, 0, 0);
        }
        return acc;
    };

    // ---- SLOW stage (Round-6 proven agent-scope LLC protocol) ----
    auto STAGE_SLOW = [&](f32x4 Yv) -> f32x4 {
        unsigned lo = (unsigned)f2bf(Yv[0]) | ((unsigned)f2bf(Yv[1]) << 16);
        unsigned hi = (unsigned)f2bf(Yv[2]) | ((unsigned)f2bf(Yv[3]) << 16);
        uint2v u; u.x = lo; u.y = hi;
        *(uint2v*)(Ylds + cl * 1024 + ((rg * 2) ^ swz)) = u;
        u64* slot = Ybuf + ((size_t)((ex & 1) * 64 + g) * 4 + q) * 512;
        __hip_atomic_store(slot + (cl * 32 + (rloc >> 2)),
                           (u64)lo | ((u64)hi << 32),
                           __ATOMIC_RELAXED, __HIP_MEMORY_SCOPE_AGENT);
        asm volatile("s_waitcnt vmcnt(0)" ::: "memory");
        __syncthreads();
        if (tid == 0) atomicAdd(cptr, 1u);
        const unsigned tgt = 4u * (unsigned)(ex + 1);
        if (wave == 0) {
            while (__hip_atomic_load(cptr, __ATOMIC_RELAXED, __HIP_MEMORY_SCOPE_AGENT) < tgt)
                __builtin_amdgcn_s_sleep(1);
        }
        __syncthreads();
        asm volatile("" ::: "memory");
        const int pcol = tid >> 5, prq = tid & 31;
        const u64* pb = Ybuf + (size_t)((ex & 1) * 64 + g) * 4 * 512;
#pragma unroll
        for (int j = 1; j <= 3; ++j) {
            const int qq = (q + j) & 3;
            u64 v = __hip_atomic_load(pb + qq * 512 + pcol * 32 + prq,
                                      __ATOMIC_RELAXED, __HIP_MEMORY_SCOPE_AGENT);
            uint2v w; w.x = (unsigned)v; w.y = (unsigned)(v >> 32);
            const int prg = qq * 128 + prq * 4;
            *(uint2v*)(Ylds + pcol * 1024 + ((prg * 2) ^ ((pcol & 7) << 4))) = w;
        }
        __syncthreads();
        f32x4 acc = do_mm();
        __syncthreads();
        ++ex;
        return Yv * (W + acc);
    };

    // ---- FAST stage (co-XCD: exchange through the shared, coherent L2) ----
    // Data: plain stores complete at L2; peer reads via opaque-zero fetch_add
    // RMWs, which EXECUTE at L2 (never read L1 -> never stale). Opaque zero
    // blocks LLVM's idempotent-RMW->load transform.
    auto STAGE_FAST = [&](f32x4 Yv) -> f32x4 {
        unsigned lo = (unsigned)f2bf(Yv[0]) | ((unsigned)f2bf(Yv[1]) << 16);
        unsigned hi = (unsigned)f2bf(Yv[2]) | ((unsigned)f2bf(Yv[3]) << 16);
        uint2v u; u.x = lo; u.y = hi;
        *(uint2v*)(Ylds + cl * 1024 + ((rg * 2) ^ swz)) = u;
        u64* slot = Ybuf + ((size_t)((ex & 1) * 64 + g) * 4 + q) * 512;
        slot[cl * 32 + (rloc >> 2)] = (u64)lo | ((u64)hi << 32);   // plain -> L2
        asm volatile("s_waitcnt vmcnt(0)" ::: "memory");           // own slice in L2
        __syncthreads();
        if (tid == 0)
            __hip_atomic_fetch_add(fbase + q * 32, 1u,
                                   __ATOMIC_RELAXED, __HIP_MEMORY_SCOPE_WORKGROUP);
        const unsigned tgt = (unsigned)(ex + 1);
        if (tid < 3) {                       // 3 lanes spin on 3 peer flags, L2 RMW
            unsigned z0 = 0; asm volatile("" : "+v"(z0));
            unsigned* pf = fbase + (((q + 1 + tid) & 3) * 32);
            while (__hip_atomic_fetch_add(pf, z0, __ATOMIC_RELAXED,
                                          __HIP_MEMORY_SCOPE_WORKGROUP) < tgt)
                __builtin_amdgcn_s_sleep(1);
        }
        __syncthreads();
        asm volatile("" ::: "memory");
        const int pcol = tid >> 5, prq = tid & 31;
        u64* pb = Ybuf + (size_t)((ex & 1) * 64 + g) * 4 * 512;
        u64 z64 = 0; asm volatile("" : "+v"(z64));
#pragma unroll
        for (int j = 1; j <= 3; ++j) {
            const int qq = (q + j) & 3;
            u64 v = __hip_atomic_fetch_add(pb + qq * 512 + pcol * 32 + prq, z64,
                                           __ATOMIC_RELAXED, __HIP_MEMORY_SCOPE_WORKGROUP);
            uint2v w; w.x = (unsigned)v; w.y = (unsigned)(v >> 32);
            const int prg = qq * 128 + prq * 4;
            *(uint2v*)(Ylds + pcol * 1024 + ((prg * 2) ^ ((pcol & 7) << 4))) = w;
        }
        __syncthreads();
        f32x4 acc = do_mm();
        __syncthreads();
        ++ex;
        return Yv * (W + acc);
    };

    auto run = [&](auto&& STG) {
#pragma unroll 1
        for (int s = 0; s < NSTEPS; ++s) {
            f32x4 K1 = STG(X0);
            f32x4 K2 = STG(X0 + HSTEP * (A21 * K1));
            f32x4 K3 = STG(X0 + HSTEP * (A31 * K1 + A32 * K2));
            f32x4 K4 = STG(X0 + HSTEP * (A41 * K1 + A42 * K2 + A43 * K3));
            f32x4 K5 = STG(X0 + HSTEP * (A51 * K1 + A52 * K2 + A53 * K3 + A54 * K4));
            f32x4 K6 = STG(X0 + HSTEP * (A61 * K1 + A62 * K2 + A63 * K3 + A64 * K4 + A65 * K5));
            X0 = X0 + HSTEP * (B1 * K1 + B3 * K3 + B4 * K4 + B5 * K5 + B6 * K6);
        }
    };
    if (fastp) run(STAGE_FAST); else run(STAGE_SLOW);

    // Fortran flatten: out[col*512 + row]
    *(f32x4*)(out + col * 512 + rg) = X0;
}

extern "C" void kernel_launch(void* const* d_in, const int* in_sizes, int n_in,
                              void* d_out, int out_size, void* d_ws, size_t ws_size,
                              hipStream_t stream)
{
    const float* x   = (const float*)d_in[0];
    const float* p   = (const float*)d_in[1];
    const float* r   = (const float*)d_in[2];
    const float* A   = (const float*)d_in[3];
    const float* eps = (const float*)d_in[4];
    float* out = (float*)d_out;

    short*    Aw    = (short*)d_ws;
    unsigned* sctr  = (unsigned*)((char*)d_ws + WS_SCTR);
    unsigned* xtab  = (unsigned*)((char*)d_ws + WS_XTAB);
    unsigned* fflag = (unsigned*)((char*)d_ws + WS_FFLAG);
    u64*      Ybuf  = (u64*)((char*)d_ws + WS_YB);

    hipMemsetAsync((char*)d_ws + WS_SCTR, 0, 48 * 1024, stream);  // sctr+xtab+fflag
    hipLaunchKernelGGL(pack_A_kernel, dim3(128), dim3(256), 0, stream, A, Aw);
    hipLaunchKernelGGL(mbpert_kernel, dim3(256), dim3(512), 0, stream,
                       x, p, r, eps, Aw, sctr, xtab, fflag, Ybuf, out);
}